// Round 1
// baseline (16406.615 us; speedup 1.0000x reference)
//
#include <hip/hip_runtime.h>
#include <math.h>

#define B_  64
#define T_  50
#define S_  50
#define U_  1024
#define E_  100
#define V_  30001
#define U4_ 4096

// ---------------------------------------------------------------------------
// Generic tiled f32 GEMM: C[M,N] = A[M,K] @ B[K,N] (+ bias).
// BM=BN=128, BK=8, 256 threads, 8x8 micro-tile.
// Requires M % 128 == 0, K % 8 == 0, lda % 4 == 0. Handles N edge and
// non-4-aligned ldb (e.g. V=30001) via a scalar load path.
// grid.x = N tiles, grid.y = M tiles.
// ---------------------------------------------------------------------------
__global__ __launch_bounds__(256) void gemm128(
    const float* __restrict__ A, int lda,
    const float* __restrict__ Bm, int ldb,
    float* __restrict__ C, int ldc,
    int N, int K, const float* __restrict__ bias)
{
    __shared__ float As[8][132];   // [k][m], padded
    __shared__ float Bs[8][132];   // [k][n], padded

    const int n0  = blockIdx.x * 128;
    const int m0  = blockIdx.y * 128;
    const int tid = threadIdx.x;
    const int tx  = tid & 15, ty = tid >> 4;

    float acc[8][8];
#pragma unroll
    for (int i = 0; i < 8; ++i)
#pragma unroll
        for (int j = 0; j < 8; ++j) acc[i][j] = 0.f;

    const int ra = tid >> 1, ca = (tid & 1) * 4;    // A tile: 128 rows x 8 k
    const int rb = tid >> 5, cb = (tid & 31) * 4;   // B tile: 8 k x 128 cols
    const bool fast_b = ((ldb & 3) == 0) && (n0 + 128 <= N);

    for (int k0 = 0; k0 < K; k0 += 8) {
        float4 av = *(const float4*)&A[(size_t)(m0 + ra) * lda + k0 + ca];
        As[ca + 0][ra] = av.x;
        As[ca + 1][ra] = av.y;
        As[ca + 2][ra] = av.z;
        As[ca + 3][ra] = av.w;

        float4 bv;
        if (fast_b) {
            bv = *(const float4*)&Bm[(size_t)(k0 + rb) * ldb + n0 + cb];
        } else {
            const float* bp = &Bm[(size_t)(k0 + rb) * ldb];
            bv.x = (n0 + cb + 0 < N) ? bp[n0 + cb + 0] : 0.f;
            bv.y = (n0 + cb + 1 < N) ? bp[n0 + cb + 1] : 0.f;
            bv.z = (n0 + cb + 2 < N) ? bp[n0 + cb + 2] : 0.f;
            bv.w = (n0 + cb + 3 < N) ? bp[n0 + cb + 3] : 0.f;
        }
        *(float4*)&Bs[rb][cb] = bv;
        __syncthreads();

#pragma unroll
        for (int kk = 0; kk < 8; ++kk) {
            float4 a0 = *(const float4*)&As[kk][ty * 4];
            float4 a1 = *(const float4*)&As[kk][64 + ty * 4];
            float4 b0 = *(const float4*)&Bs[kk][tx * 4];
            float4 b1 = *(const float4*)&Bs[kk][64 + tx * 4];
            float a_[8] = {a0.x, a0.y, a0.z, a0.w, a1.x, a1.y, a1.z, a1.w};
            float b_[8] = {b0.x, b0.y, b0.z, b0.w, b1.x, b1.y, b1.z, b1.w};
#pragma unroll
            for (int i = 0; i < 8; ++i)
#pragma unroll
                for (int j = 0; j < 8; ++j)
                    acc[i][j] = fmaf(a_[i], b_[j], acc[i][j]);
        }
        __syncthreads();
    }

#pragma unroll
    for (int i = 0; i < 8; ++i) {
        int row = m0 + ((i < 4) ? (ty * 4 + i) : (64 + ty * 4 + (i - 4)));
#pragma unroll
        for (int j = 0; j < 8; ++j) {
            int col = n0 + ((j < 4) ? (tx * 4 + j) : (64 + tx * 4 + (j - 4)));
            if (col < N) {
                float v = acc[i][j];
                if (bias) v += bias[col];
                C[(size_t)row * ldc + col] = v;
            }
        }
    }
}

// ---------------------------------------------------------------------------
// Wcomb[0:1024,:] += Uh  (elementwise)
// ---------------------------------------------------------------------------
__global__ void add_inplace(float* __restrict__ dst, const float* __restrict__ src, int n)
{
    int i = blockIdx.x * blockDim.x + threadIdx.x;
    if (i < n) dst[i] += src[i];
}

// ---------------------------------------------------------------------------
// Split-K recurrent GEMM: zp[(ks*64 + b)*4096 + n] = sum_{k in slice} A[b*lda+k] * B[k*4096+n]
// grid = (64 n-tiles, KS k-slices of 256), 256 threads.
// BM=64 (all batches), BN=64, BK=16.
// ---------------------------------------------------------------------------
__global__ __launch_bounds__(256) void zgemm_partial(
    const float* __restrict__ A, int lda,
    const float* __restrict__ Bm,
    float* __restrict__ zp)
{
    __shared__ float As[64][17];
    __shared__ float Bs[16][68];

    const int n0     = blockIdx.x * 64;
    const int ks     = blockIdx.y;
    const int k_base = ks * 256;
    const int tid    = threadIdx.x;
    const int tx     = tid & 15, ty = tid >> 4;

    float acc[4][4];
#pragma unroll
    for (int i = 0; i < 4; ++i)
#pragma unroll
        for (int j = 0; j < 4; ++j) acc[i][j] = 0.f;

    const int ra = tid >> 2, ca = (tid & 3) * 4;   // A tile: 64 rows x 16 k
    const int rb = tid >> 4, cb = (tid & 15) * 4;  // B tile: 16 k x 64 cols

    for (int kt = 0; kt < 16; ++kt) {
        const int k0 = k_base + kt * 16;
        float4 av = *(const float4*)&A[(size_t)ra * lda + k0 + ca];
        As[ra][ca + 0] = av.x;
        As[ra][ca + 1] = av.y;
        As[ra][ca + 2] = av.z;
        As[ra][ca + 3] = av.w;
        float4 bv = *(const float4*)&Bm[(size_t)(k0 + rb) * U4_ + n0 + cb];
        *(float4*)&Bs[rb][cb] = bv;
        __syncthreads();
#pragma unroll
        for (int kk = 0; kk < 16; ++kk) {
            float a_[4];
#pragma unroll
            for (int i = 0; i < 4; ++i) a_[i] = As[ty * 4 + i][kk];
            float4 bq = *(const float4*)&Bs[kk][tx * 4];
            float b_[4] = {bq.x, bq.y, bq.z, bq.w};
#pragma unroll
            for (int i = 0; i < 4; ++i)
#pragma unroll
                for (int j = 0; j < 4; ++j)
                    acc[i][j] = fmaf(a_[i], b_[j], acc[i][j]);
        }
        __syncthreads();
    }

#pragma unroll
    for (int i = 0; i < 4; ++i) {
        float4 v = make_float4(acc[i][0], acc[i][1], acc[i][2], acc[i][3]);
        *(float4*)&zp[(size_t)(ks * 64 + ty * 4 + i) * U4_ + n0 + tx * 4] = v;
    }
}

// ---------------------------------------------------------------------------
// Fused per-step kernel: reduce z partials + embedding term + bias, LSTM gates,
// Luong score/softmax/context, write hc_all[t] = [h_t (1024) | ctx_t (1024)].
// grid = 64 (batch), 1024 threads.
// ---------------------------------------------------------------------------
__global__ __launch_bounds__(1024) void gates_attn(
    const int*   __restrict__ tokens,
    const float* __restrict__ emb,
    const float* __restrict__ Wx,     // [1124, 4096]
    const float* __restrict__ bvec,   // [4096]
    const float* __restrict__ zp, int KS,
    const float* __restrict__ c_in,
    float*       __restrict__ c_out,
    const float* __restrict__ keys,   // [64,50,1024]
    const float* __restrict__ memory, // [64,50,1024]
    float*       __restrict__ hc_row, // hc_all + t*2048 (row stride T*2048)
    int t)
{
    __shared__ float xe[E_];
    __shared__ float hs[U_];
    __shared__ float sc[64];
    __shared__ float al[64];

    const int b = blockIdx.x;
    const int u = threadIdx.x;

    if (u < E_) xe[u] = emb[(size_t)tokens[b * T_ + t] * E_ + u];
    __syncthreads();

    // z for the 4 gates (i, f, g, o)
    float zg[4];
#pragma unroll
    for (int g = 0; g < 4; ++g) {
        const int col = g * U_ + u;
        float a = bvec[col];
        for (int ks = 0; ks < KS; ++ks)
            a += zp[(size_t)(ks * 64 + b) * U4_ + col];
        float a2 = 0.f;
        for (int e = 0; e < E_; ++e)
            a2 = fmaf(xe[e], Wx[(size_t)e * U4_ + col], a2);
        zg[g] = a + a2;
    }

    const float si = 1.f / (1.f + expf(-zg[0]));
    const float sf = 1.f / (1.f + expf(-zg[1]));
    const float tg = tanhf(zg[2]);
    const float so = 1.f / (1.f + expf(-zg[3]));

    const float c_prev = c_in[(size_t)b * U_ + u];
    const float c_new  = sf * c_prev + si * tg;
    const float h_new  = so * tanhf(c_new);

    c_out[(size_t)b * U_ + u] = c_new;
    hs[u] = h_new;
    hc_row[(size_t)b * (T_ * 2048) + u] = h_new;
    __syncthreads();

    // scores: score[s] = dot(h_new, keys[b,s,:])
    const int lane = u & 63, w = u >> 6;   // 16 waves
    for (int s = w; s < S_; s += 16) {
        const float* kp = &keys[((size_t)b * S_ + s) * U_];
        float p = 0.f;
#pragma unroll
        for (int i = 0; i < 16; ++i)
            p = fmaf(hs[lane + i * 64], kp[lane + i * 64], p);
#pragma unroll
        for (int off = 32; off > 0; off >>= 1)
            p += __shfl_xor(p, off);
        if (lane == 0) sc[s] = p;
    }
    __syncthreads();

    // softmax over 50 (single wave)
    if (u < 64) {
        float v = (lane < S_) ? sc[lane] : -INFINITY;
        float m = v;
#pragma unroll
        for (int off = 32; off > 0; off >>= 1)
            m = fmaxf(m, __shfl_xor(m, off));
        float e = (lane < S_) ? expf(v - m) : 0.f;
        float ssum = e;
#pragma unroll
        for (int off = 32; off > 0; off >>= 1)
            ssum += __shfl_xor(ssum, off);
        if (lane < S_) al[lane] = e / ssum;
    }
    __syncthreads();

    // ctx[u] = sum_s align[s] * memory[b,s,u]
    float cacc = 0.f;
    for (int s = 0; s < S_; ++s)
        cacc = fmaf(al[s], memory[((size_t)b * S_ + s) * U_ + u], cacc);
    hc_row[(size_t)b * (T_ * 2048) + U_ + u] = cacc;
}

// ---------------------------------------------------------------------------
extern "C" void kernel_launch(void* const* d_in, const int* in_sizes, int n_in,
                              void* d_out, int out_size, void* d_ws, size_t ws_size,
                              hipStream_t stream)
{
    const int*   tokens = (const int*)  d_in[0];
    const float* memory = (const float*)d_in[1];
    const float* h0     = (const float*)d_in[2];
    const float* c0     = (const float*)d_in[3];
    const float* emb    = (const float*)d_in[4];
    const float* Wx     = (const float*)d_in[5];
    const float* Uh     = (const float*)d_in[6];
    const float* bvec   = (const float*)d_in[7];
    const float* Wm     = (const float*)d_in[8];
    const float* Wa     = (const float*)d_in[9];
    const float* Wo     = (const float*)d_in[10];
    const float* bo     = (const float*)d_in[11];
    float* out = (float*)d_out;

    // workspace layout (floats)
    float* ws = (float*)d_ws;
    size_t off = 0;
    float* keys     = ws + off; off += (size_t)B_ * S_ * U_;   // 3,276,800
    float* Wcomb    = ws + off; off += (size_t)2048 * U4_;     // 8,388,608
    float* hc_all   = ws + off; off += (size_t)B_ * T_ * 2048; // 6,553,600
    float* cbuf     = ws + off; off += (size_t)B_ * U_;        //    65,536
    float* zp       = ws + off; off += (size_t)8 * B_ * U4_;   // 2,097,152
    float* attn_all = keys;  // keys dead after the loop; alias (both 13.1 MB)

    // 1. Wcomb = Wa @ Wx[E:, :]   (M=2048, N=4096, K=1024)
    gemm128<<<dim3(32, 16), 256, 0, stream>>>(
        Wa, U_, Wx + (size_t)E_ * U4_, U4_, Wcomb, U4_, U4_, U_, nullptr);
    // 2. Wcomb[0:1024, :] += Uh
    add_inplace<<<(1024 * U4_) / 256, 256, 0, stream>>>(Wcomb, Uh, 1024 * U4_);
    // 3. keys = memory @ Wm   (M=3200, N=1024, K=1024)
    gemm128<<<dim3(8, 25), 256, 0, stream>>>(
        memory, U_, Wm, U_, keys, U_, U_, U_, nullptr);

    // 4. recurrent loop: 2 kernels per step
    for (int t = 0; t < T_; ++t) {
        const float* Azg = (t == 0) ? h0 : (hc_all + (size_t)(t - 1) * 2048);
        const int    lda = (t == 0) ? U_ : T_ * 2048;
        const float* Bzg = (t == 0) ? Uh : Wcomb;   // t=0: attn=0 -> pure Uh, K=1024
        const int    KS  = (t == 0) ? 4 : 8;
        zgemm_partial<<<dim3(64, KS), 256, 0, stream>>>(Azg, lda, Bzg, zp);
        gates_attn<<<B_, 1024, 0, stream>>>(
            tokens, emb, Wx, bvec, zp, KS,
            (t == 0) ? c0 : cbuf, cbuf, keys, memory,
            hc_all + (size_t)t * 2048, t);
    }

    // 5. attn_all = hc_all @ Wa   (M=3200, N=1024, K=2048)
    gemm128<<<dim3(8, 25), 256, 0, stream>>>(
        hc_all, 2048, Wa, U_, attn_all, U_, U_, 2048, nullptr);
    // 6. out = attn_all @ Wo + bo   (M=3200, N=30001, K=1024)
    gemm128<<<dim3(235, 25), 256, 0, stream>>>(
        attn_all, U_, Wo, V_, out, V_, V_, U_, bo);
}